// Round 4
// baseline (243.298 us; speedup 1.0000x reference)
//
#include <hip/hip_runtime.h>

// CIF (continuous integrate-and-fire) — MI355X
//
// d_out layout: [0..T*H) frame_sel ; [T*H..T*H+B) integ_new ; then [B*H) frame_new
//
// K1 prep (ONE block x 512 threads — fused transpose + chain + replay):
//   A: all threads transpose alphas [B,T] -> aT4 [T/4][B] (float4 granules) in ws.
//   B: wave 0 runs the irreducible serial recurrence  s = integ + alpha ;
//      integ = fract(s)  — bit-exact vs reference's  fire=s>=1 ; integ'=fire?s-1:s
//      for s in [0,2) (Sterbenz: fract(s)=s-1.0 exact). Double-buffered register
//      prefetch (2x16 float4; 512-thread block => 256-VGPR budget, no spill).
//      Per-64-step-chunk boundary integ values go to LDS.
//   C: all threads replay chunks bit-exactly from LDS boundaries -> gT [T][B],
//      per-chunk fire masks in LDS; then batch-0 fire list (popcount + wave
//      prefix scan), tlast[b], and per-output-row segment metadata.
// K2 out: parallel segment sums (unchanged from R1/R2 — passed absmax 0).

#define THRESH 1.0f
#define MAXB   64
#define MAXT   2048
#define MAXCH  (MAXT / 64)

__device__ __forceinline__ float fract_exact(float x) {
    float r; asm("v_fract_f32 %0, %1" : "=v"(r) : "v"(x)); return r;
}

__global__ __launch_bounds__(512) void cif_prep_kernel(
    const float4* __restrict__ a4,      // alphas as float4, [B * T/4]
    const float*  __restrict__ integ0,  // [B]
    float4* __restrict__ aT4,           // ws [T/4][B]
    float*  __restrict__ gT,            // ws [T][B]
    int* __restrict__ rowStart, int* __restrict__ rowEnd, int* __restrict__ rowFlags, // [T]
    int* __restrict__ tlast,            // [B]
    float* __restrict__ integ_out,      // d_out + T*H
    int B, int T)
{
    const int tid = threadIdx.x;
    const int T4 = T >> 2;
    const int nchunk = T >> 6;

    __shared__ float              s_ci[MAXCH * MAXB];   // chunk-boundary integ
    __shared__ unsigned long long s_mask[MAXCH * MAXB]; // per-chunk fire masks
    __shared__ int                s_fire[MAXT];
    __shared__ int                s_nf, s_f0;

    // ---- Phase A: transpose alphas -> aT4 (coalesced reads) ----
    for (int i = tid; i < B * T4; i += 512) {
        const int b = i / T4, c = i - b * T4;
        aT4[(size_t)c * B + b] = a4[i];
    }
    __syncthreads();   // block-level visibility of aT4

    // ---- Phase B: serial chain, wave 0 only ----
    if (tid < 64) {
        const int lane = tid;
        const bool act = lane < B;
        float integ = act ? integ0[lane] : 0.0f;
        float4 bufA[16], bufB[16];

#define LOADCH(buf, c) do { if (act) { \
        _Pragma("unroll") for (int j = 0; j < 16; ++j) \
            buf[j] = aT4[(size_t)((c) * 16 + j) * B + lane]; } } while (0)

#define DOCH(buf, c) do { if (act) { \
        s_ci[(c) * B + lane] = integ; \
        _Pragma("unroll") for (int j = 0; j < 16; ++j) { \
            integ = fract_exact(integ + buf[j].x); \
            integ = fract_exact(integ + buf[j].y); \
            integ = fract_exact(integ + buf[j].z); \
            integ = fract_exact(integ + buf[j].w); \
        } } } while (0)

        LOADCH(bufA, 0);
        for (int c = 0; c < nchunk; c += 2) {
            if (c + 1 < nchunk) LOADCH(bufB, c + 1);
            DOCH(bufA, c);
            if (c + 2 < nchunk) LOADCH(bufA, c + 2);
            if (c + 1 < nchunk) DOCH(bufB, c + 1);
        }
#undef LOADCH
#undef DOCH
        if (act) integ_out[lane] = integ;
    }
    __syncthreads();

    // ---- Phase C: bit-exact replay, all threads ----
    for (int w = tid; w < nchunk * B; w += 512) {
        const int c = w / B, b = w - c * B;    // b fastest -> coalesced
        float integ = s_ci[w];
        unsigned long long m = 0;
        for (int j = 0; j < 16; ++j) {
            const float4 av4 = aT4[(size_t)(c * 16 + j) * B + b];
            const float av[4] = {av4.x, av4.y, av4.z, av4.w};
            float gv[4];
#pragma unroll
            for (int k = 0; k < 4; ++k) {
                const int idx = j * 4 + k;
                const float alpha = av[k];
                const float s   = integ + alpha;   // exact ref op order
                const bool fire = (s >= THRESH);
                const float sm1 = s - 1.0f;
                integ = fire ? sm1 : s;
                gv[k] = fire ? sm1 : alpha;        // == reference rem to 1 ulp
                m |= fire ? (1ull << idx) : 0ull;
            }
#pragma unroll
            for (int k = 0; k < 4; ++k)
                gT[(size_t)(c * 64 + j * 4 + k) * B + b] = gv[k];
        }
        s_mask[w] = m;
    }
    __syncthreads();

    // ---- tlast[b] + batch-0 fire list (wave 0) ----
    if (tid < B) {
        int tl = -1;
        for (int c = nchunk - 1; c >= 0; --c) {
            const unsigned long long mc = s_mask[c * B + tid];
            if (mc) { tl = c * 64 + 63 - __clzll(mc); break; }
        }
        tlast[tid] = tl;
    }
    if (tid < 64) {
        unsigned long long m0 = (tid < nchunk) ? s_mask[tid * B] : 0ull;
        const int pc = __popcll(m0);
        int x = pc;
#pragma unroll
        for (int d = 1; d < 64; d <<= 1) {
            const int y = __shfl_up(x, d);
            if (tid >= d) x += y;
        }
        if (tid == 63) s_nf = x;
        if (tid == 0)  s_f0 = (int)(m0 & 1ull);
        int r = x - pc;
        while (m0) {
            const int p = __ffsll(m0) - 1;
            s_fire[r++] = tid * 64 + p;
            m0 &= m0 - 1;
        }
    }
    __syncthreads();

    // ---- per-output-row segment metadata ----
    const int nf = s_nf, f0 = s_f0;
    for (int r = tid; r < T; r += 512) {
        int st, en, fl;
        if (r < nf) {
            en = s_fire[r];
            st = (r == 0) ? 0 : s_fire[r - 1];
            fl = ((r == 0) ? 1 : 0) | 2;   // bit0: add frame0, bit1: end is a fire
        } else {                            // padding row -> frames[0][0]
            st = 0; en = 0; fl = 1 | (f0 ? 2 : 0);
        }
        rowStart[r] = st; rowEnd[r] = en; rowFlags[r] = fl;
    }
}

__global__ __launch_bounds__(128) void cif_out_kernel(
    const float* __restrict__ hidden,   // [B,T,H]
    const float* __restrict__ frame0,   // [B,H]
    const float* __restrict__ gT,       // [T][B]
    const float* __restrict__ alphas,   // [B,T] (batch-0 row used for wend)
    const int* __restrict__ rowStart, const int* __restrict__ rowEnd,
    const int* __restrict__ rowFlags, const int* __restrict__ tlast,
    float* __restrict__ out_sel,        // [T,H]
    float* __restrict__ frame_out,      // [B,H]
    int B, int T, int H)
{
    const int blk = blockIdx.x;

    if (blk < T) {
        const int r = blk;
        const int start = rowStart[r], end = rowEnd[r], fl = rowFlags[r];
        const float a  = alphas[end];                  // batch 0
        const float ge = gT[(size_t)end * B];
        const float wend = (fl & 2) ? (a - ge) : a;    // cur at end
        for (int h0 = threadIdx.x * 4; h0 < H; h0 += 128 * 4) {
            float4 acc = (fl & 1) ? *reinterpret_cast<const float4*>(frame0 + h0)
                                  : make_float4(0.f, 0.f, 0.f, 0.f);
            for (int s = start; s < end; ++s) {
                const float  w  = gT[(size_t)s * B];
                const float4 hv = *reinterpret_cast<const float4*>(hidden + (size_t)s * H + h0);
                acc.x += w * hv.x; acc.y += w * hv.y;
                acc.z += w * hv.z; acc.w += w * hv.w;
            }
            const float4 hv = *reinterpret_cast<const float4*>(hidden + (size_t)end * H + h0);
            acc.x += wend * hv.x; acc.y += wend * hv.y;
            acc.z += wend * hv.z; acc.w += wend * hv.w;
            *reinterpret_cast<float4*>(out_sel + (size_t)r * H + h0) = acc;
        }
    } else {
        const int b  = blk - T;
        const int tl = tlast[b];
        const int start = (tl < 0) ? 0 : tl;
        const float* hb = hidden + (size_t)b * T * H;
        for (int h0 = threadIdx.x * 4; h0 < H; h0 += 128 * 4) {
            float4 acc = (tl < 0) ? *reinterpret_cast<const float4*>(frame0 + (size_t)b * H + h0)
                                  : make_float4(0.f, 0.f, 0.f, 0.f);
            for (int s = start; s < T; ++s) {
                const float  w  = gT[(size_t)s * B + b];
                const float4 hv = *reinterpret_cast<const float4*>(hb + (size_t)s * H + h0);
                acc.x += w * hv.x; acc.y += w * hv.y;
                acc.z += w * hv.z; acc.w += w * hv.w;
            }
            *reinterpret_cast<float4*>(frame_out + (size_t)b * H + h0) = acc;
        }
    }
}

extern "C" void kernel_launch(void* const* d_in, const int* in_sizes, int n_in,
                              void* d_out, int out_size, void* d_ws, size_t ws_size,
                              hipStream_t stream) {
    const float* hidden    = (const float*)d_in[0]; // [B,T,H]
    const float* alphas    = (const float*)d_in[1]; // [B,T]
    const float* integrate = (const float*)d_in[2]; // [B]
    const float* frame     = (const float*)d_in[3]; // [B,H]

    const int B = in_sizes[2];
    const int T = in_sizes[1] / B;
    const int H = in_sizes[3] / B;

    float* out       = (float*)d_out;
    float* out_sel   = out;                     // T*H
    float* integ_out = out + (size_t)T * H;     // B
    float* frame_out = integ_out + B;           // B*H

    char* ws = (char*)d_ws;
    float4* aT4   = (float4*)ws;  ws += sizeof(float) * (size_t)B * T;
    float*  gT    = (float*)ws;   ws += sizeof(float) * (size_t)B * T;
    int* rowStart = (int*)ws;     ws += sizeof(int) * T;
    int* rowEnd   = (int*)ws;     ws += sizeof(int) * T;
    int* rowFlags = (int*)ws;     ws += sizeof(int) * T;
    int* tlast    = (int*)ws;     ws += sizeof(int) * B;

    cif_prep_kernel<<<1, 512, 0, stream>>>(
        (const float4*)alphas, integrate, aT4, gT,
        rowStart, rowEnd, rowFlags, tlast, integ_out, B, T);

    cif_out_kernel<<<T + B, 128, 0, stream>>>(
        hidden, frame, gT, alphas, rowStart, rowEnd, rowFlags, tlast,
        out_sel, frame_out, B, T, H);
}

// Round 5
// 242.625 us; speedup vs baseline: 1.0028x; 1.0028x over previous
//
#include <hip/hip_runtime.h>

// CIF (continuous integrate-and-fire) — MI355X
//
// d_out layout: [0..T*H) frame_sel ; [T*H..T*H+B) integ_new ; then [B*H) frame_new
//
// K1 prep (ONE block x 512 threads, __launch_bounds__(512,2) => 256-VGPR budget so
//          the chain's 2x16 float4 prefetch buffers stay in registers — R4's 68-VGPR
//          allocation spilled them to scratch and cost ~75 us in the serial loop):
//   A: all threads transpose alphas [B,T] -> aT4 [T/4][B] (float4 granules) in ws.
//   B: wave 0 runs the irreducible serial recurrence  s = integ + alpha ;
//      integ = fract(s)  — bit-exact vs reference's  fire=s>=1 ; integ'=fire?s-1:s
//      for s in [0,2) (Sterbenz: fract(s)=s-1.0 exact). Double-buffered register
//      prefetch; per-64-step-chunk boundary integ values go to LDS.
//   C: all threads replay chunks bit-exactly from LDS boundaries -> gT [T][B],
//      per-chunk fire masks in LDS; then batch-0 fire list (popcount + wave
//      prefix scan), tlast[b], and per-output-row segment metadata.
// K2 out: parallel segment sums (unchanged since R1 — passed absmax 0 each round).

#define THRESH 1.0f
#define MAXB   64
#define MAXT   2048
#define MAXCH  (MAXT / 64)

__device__ __forceinline__ float fract_exact(float x) {
    float r; asm("v_fract_f32 %0, %1" : "=v"(r) : "v"(x)); return r;
}

__global__ __launch_bounds__(512, 2) void cif_prep_kernel(
    const float4* __restrict__ a4,      // alphas as float4, [B * T/4]
    const float*  __restrict__ integ0,  // [B]
    float4* __restrict__ aT4,           // ws [T/4][B]
    float*  __restrict__ gT,            // ws [T][B]
    int* __restrict__ rowStart, int* __restrict__ rowEnd, int* __restrict__ rowFlags, // [T]
    int* __restrict__ tlast,            // [B]
    float* __restrict__ integ_out,      // d_out + T*H
    int B, int T)
{
    const int tid = threadIdx.x;
    const int T4 = T >> 2;
    const int nchunk = T >> 6;

    __shared__ float              s_ci[MAXCH * MAXB];   // chunk-boundary integ
    __shared__ unsigned long long s_mask[MAXCH * MAXB]; // per-chunk fire masks
    __shared__ int                s_fire[MAXT];
    __shared__ int                s_nf, s_f0;

    // ---- Phase A: transpose alphas -> aT4 (coalesced reads) ----
    for (int i = tid; i < B * T4; i += 512) {
        const int b = i / T4, c = i - b * T4;
        aT4[(size_t)c * B + b] = a4[i];
    }
    __syncthreads();   // block-level visibility of aT4

    // ---- Phase B: serial chain, wave 0 only ----
    if (tid < 64) {
        const int lane = tid;
        const bool act = lane < B;
        float integ = act ? integ0[lane] : 0.0f;
        float4 bufA[16], bufB[16];

#define LOADCH(buf, c) do { if (act) { \
        _Pragma("unroll") for (int j = 0; j < 16; ++j) \
            buf[j] = aT4[(size_t)((c) * 16 + j) * B + lane]; } } while (0)

#define DOCH(buf, c) do { if (act) { \
        s_ci[(c) * B + lane] = integ; \
        _Pragma("unroll") for (int j = 0; j < 16; ++j) { \
            integ = fract_exact(integ + buf[j].x); \
            integ = fract_exact(integ + buf[j].y); \
            integ = fract_exact(integ + buf[j].z); \
            integ = fract_exact(integ + buf[j].w); \
        } } } while (0)

        LOADCH(bufA, 0);
        for (int c = 0; c < nchunk; c += 2) {
            if (c + 1 < nchunk) LOADCH(bufB, c + 1);
            DOCH(bufA, c);
            if (c + 2 < nchunk) LOADCH(bufA, c + 2);
            if (c + 1 < nchunk) DOCH(bufB, c + 1);
        }
#undef LOADCH
#undef DOCH
        if (act) integ_out[lane] = integ;
    }
    __syncthreads();

    // ---- Phase C: bit-exact replay, all threads ----
    for (int w = tid; w < nchunk * B; w += 512) {
        const int c = w / B, b = w - c * B;    // b fastest -> coalesced
        float integ = s_ci[w];
        unsigned long long m = 0;
        for (int j = 0; j < 16; ++j) {
            const float4 av4 = aT4[(size_t)(c * 16 + j) * B + b];
            const float av[4] = {av4.x, av4.y, av4.z, av4.w};
            float gv[4];
#pragma unroll
            for (int k = 0; k < 4; ++k) {
                const int idx = j * 4 + k;
                const float alpha = av[k];
                const float s   = integ + alpha;   // exact ref op order
                const bool fire = (s >= THRESH);
                const float sm1 = s - 1.0f;
                integ = fire ? sm1 : s;
                gv[k] = fire ? sm1 : alpha;        // == reference rem to 1 ulp
                m |= fire ? (1ull << idx) : 0ull;
            }
#pragma unroll
            for (int k = 0; k < 4; ++k)
                gT[(size_t)(c * 64 + j * 4 + k) * B + b] = gv[k];
        }
        s_mask[w] = m;
    }
    __syncthreads();

    // ---- tlast[b] + batch-0 fire list (wave 0) ----
    if (tid < B) {
        int tl = -1;
        for (int c = nchunk - 1; c >= 0; --c) {
            const unsigned long long mc = s_mask[c * B + tid];
            if (mc) { tl = c * 64 + 63 - __clzll(mc); break; }
        }
        tlast[tid] = tl;
    }
    if (tid < 64) {
        unsigned long long m0 = (tid < nchunk) ? s_mask[tid * B] : 0ull;
        const int pc = __popcll(m0);
        int x = pc;
#pragma unroll
        for (int d = 1; d < 64; d <<= 1) {
            const int y = __shfl_up(x, d);
            if (tid >= d) x += y;
        }
        if (tid == 63) s_nf = x;
        if (tid == 0)  s_f0 = (int)(m0 & 1ull);
        int r = x - pc;
        while (m0) {
            const int p = __ffsll(m0) - 1;
            s_fire[r++] = tid * 64 + p;
            m0 &= m0 - 1;
        }
    }
    __syncthreads();

    // ---- per-output-row segment metadata ----
    const int nf = s_nf, f0 = s_f0;
    for (int r = tid; r < T; r += 512) {
        int st, en, fl;
        if (r < nf) {
            en = s_fire[r];
            st = (r == 0) ? 0 : s_fire[r - 1];
            fl = ((r == 0) ? 1 : 0) | 2;   // bit0: add frame0, bit1: end is a fire
        } else {                            // padding row -> frames[0][0]
            st = 0; en = 0; fl = 1 | (f0 ? 2 : 0);
        }
        rowStart[r] = st; rowEnd[r] = en; rowFlags[r] = fl;
    }
}

__global__ __launch_bounds__(128) void cif_out_kernel(
    const float* __restrict__ hidden,   // [B,T,H]
    const float* __restrict__ frame0,   // [B,H]
    const float* __restrict__ gT,       // [T][B]
    const float* __restrict__ alphas,   // [B,T] (batch-0 row used for wend)
    const int* __restrict__ rowStart, const int* __restrict__ rowEnd,
    const int* __restrict__ rowFlags, const int* __restrict__ tlast,
    float* __restrict__ out_sel,        // [T,H]
    float* __restrict__ frame_out,      // [B,H]
    int B, int T, int H)
{
    const int blk = blockIdx.x;

    if (blk < T) {
        const int r = blk;
        const int start = rowStart[r], end = rowEnd[r], fl = rowFlags[r];
        const float a  = alphas[end];                  // batch 0
        const float ge = gT[(size_t)end * B];
        const float wend = (fl & 2) ? (a - ge) : a;    // cur at end
        for (int h0 = threadIdx.x * 4; h0 < H; h0 += 128 * 4) {
            float4 acc = (fl & 1) ? *reinterpret_cast<const float4*>(frame0 + h0)
                                  : make_float4(0.f, 0.f, 0.f, 0.f);
            for (int s = start; s < end; ++s) {
                const float  w  = gT[(size_t)s * B];
                const float4 hv = *reinterpret_cast<const float4*>(hidden + (size_t)s * H + h0);
                acc.x += w * hv.x; acc.y += w * hv.y;
                acc.z += w * hv.z; acc.w += w * hv.w;
            }
            const float4 hv = *reinterpret_cast<const float4*>(hidden + (size_t)end * H + h0);
            acc.x += wend * hv.x; acc.y += wend * hv.y;
            acc.z += wend * hv.z; acc.w += wend * hv.w;
            *reinterpret_cast<float4*>(out_sel + (size_t)r * H + h0) = acc;
        }
    } else {
        const int b  = blk - T;
        const int tl = tlast[b];
        const int start = (tl < 0) ? 0 : tl;
        const float* hb = hidden + (size_t)b * T * H;
        for (int h0 = threadIdx.x * 4; h0 < H; h0 += 128 * 4) {
            float4 acc = (tl < 0) ? *reinterpret_cast<const float4*>(frame0 + (size_t)b * H + h0)
                                  : make_float4(0.f, 0.f, 0.f, 0.f);
            for (int s = start; s < T; ++s) {
                const float  w  = gT[(size_t)s * B + b];
                const float4 hv = *reinterpret_cast<const float4*>(hb + (size_t)s * H + h0);
                acc.x += w * hv.x; acc.y += w * hv.y;
                acc.z += w * hv.z; acc.w += w * hv.w;
            }
            *reinterpret_cast<float4*>(frame_out + (size_t)b * H + h0) = acc;
        }
    }
}

extern "C" void kernel_launch(void* const* d_in, const int* in_sizes, int n_in,
                              void* d_out, int out_size, void* d_ws, size_t ws_size,
                              hipStream_t stream) {
    const float* hidden    = (const float*)d_in[0]; // [B,T,H]
    const float* alphas    = (const float*)d_in[1]; // [B,T]
    const float* integrate = (const float*)d_in[2]; // [B]
    const float* frame     = (const float*)d_in[3]; // [B,H]

    const int B = in_sizes[2];
    const int T = in_sizes[1] / B;
    const int H = in_sizes[3] / B;

    float* out       = (float*)d_out;
    float* out_sel   = out;                     // T*H
    float* integ_out = out + (size_t)T * H;     // B
    float* frame_out = integ_out + B;           // B*H

    char* ws = (char*)d_ws;
    float4* aT4   = (float4*)ws;  ws += sizeof(float) * (size_t)B * T;
    float*  gT    = (float*)ws;   ws += sizeof(float) * (size_t)B * T;
    int* rowStart = (int*)ws;     ws += sizeof(int) * T;
    int* rowEnd   = (int*)ws;     ws += sizeof(int) * T;
    int* rowFlags = (int*)ws;     ws += sizeof(int) * T;
    int* tlast    = (int*)ws;     ws += sizeof(int) * B;

    cif_prep_kernel<<<1, 512, 0, stream>>>(
        (const float4*)alphas, integrate, aT4, gT,
        rowStart, rowEnd, rowFlags, tlast, integ_out, B, T);

    cif_out_kernel<<<T + B, 128, 0, stream>>>(
        hidden, frame, gT, alphas, rowStart, rowEnd, rowFlags, tlast,
        out_sel, frame_out, B, T, H);
}

// Round 6
// 227.713 us; speedup vs baseline: 1.0684x; 1.0655x over previous
//
#include <hip/hip_runtime.h>

// CIF (continuous integrate-and-fire) — MI355X
//
// d_out layout: [0..T*H) frame_sel ; [T*H..T*H+B) integ_new ; then [B*H) frame_new
//
// K1 prep (ONE block x 512 threads):
//   A: all threads transpose alphas [B,T] -> aT4 [T/4][B] (float4 granules) in ws.
//   B: producer/consumer superchunk pipeline. Waves 1..7 copy superchunk sc+1
//      (32 KB of aT4) into the idle LDS buffer while wave 0 advances the
//      irreducible serial recurrence  s = integ + alpha ; integ = fract(s)
//      (bit-exact vs reference:  fire = s>=1 ; integ' = fire ? s-1 : s  for
//      s in [0,2), Sterbenz) out of the current LDS buffer. One barrier per
//      superchunk. Chain loads 16 float4/chunk LDS->reg, pinned ahead of the
//      compute with sched_barrier(0) (R4/R5 lesson: source-level global
//      prefetch gets sunk by LLVM; cross-wave LDS staging cannot be).
//      Per-64-step-chunk boundary integ values go to LDS (s_ci).
//   C: all threads replay chunks bit-exactly from s_ci -> gT [T][B], per-chunk
//      fire masks; then batch-0 fire list (popcount + wave prefix scan),
//      tlast[b], and per-output-row segment metadata.
// K2 out: parallel segment sums (unchanged since R1 — absmax 0 every round).

#define THRESH 1.0f
#define MAXB   64
#define MAXT   2048
#define MAXCH  (MAXT / 64)
#define SC4    2048            // float4s per superchunk buffer (32 KB)

__device__ __forceinline__ float fract_exact(float x) {
    float r; asm("v_fract_f32 %0, %1" : "=v"(r) : "v"(x)); return r;
}

__global__ __launch_bounds__(512, 2) void cif_prep_kernel(
    const float4* __restrict__ a4,      // alphas as float4, [B * T/4]
    const float*  __restrict__ integ0,  // [B]
    float4* __restrict__ aT4,           // ws [T/4][B]
    float*  __restrict__ gT,            // ws [T][B]
    int* __restrict__ rowStart, int* __restrict__ rowEnd, int* __restrict__ rowFlags, // [T]
    int* __restrict__ tlast,            // [B]
    float* __restrict__ integ_out,      // d_out + T*H
    int B, int T)
{
    const int tid = threadIdx.x;
    const int T4 = T >> 2;
    const int nchunk = T >> 6;

    __shared__ float4             s_abuf0[SC4];        // 32 KB
    __shared__ float4             s_abuf1[SC4];        // 32 KB
    __shared__ float              s_ci[MAXCH * MAXB];  // chunk-boundary integ (8 KB)
    __shared__ unsigned long long s_mask[MAXCH * MAXB];// per-chunk fire masks (16 KB)
    __shared__ int                s_fire[MAXT];        // 8 KB
    __shared__ int                s_nf, s_f0;

    // ---- Phase A: transpose alphas -> aT4 (coalesced reads) ----
    for (int i = tid; i < B * T4; i += 512) {
        const int b = i / T4, c = i - b * T4;
        aT4[(size_t)c * B + b] = a4[i];
    }
    __syncthreads();

    // ---- Phase B: superchunk pipeline ----
    // SPS steps per superchunk = SC4*4/B ; NSC superchunks = T/SPS.
    const int SPS = (SC4 * 4) / B;          // 256 for B=32
    const int NSC = T / SPS;                // 8  for T=2048
    const int cpsc = SPS >> 6;              // chunks per superchunk (4)

    // preload superchunk 0
    for (int i = tid; i < SC4; i += 512) s_abuf0[i] = aT4[i];
    __syncthreads();

    float integ = (tid < B) ? integ0[tid] : 0.0f;

    for (int sc = 0; sc < NSC; ++sc) {
        if (tid >= 64) {
            // producers: fill the other buffer with superchunk sc+1
            if (sc + 1 < NSC) {
                const float4* src = aT4 + (size_t)(sc + 1) * SC4;
                float4* dst = (sc & 1) ? s_abuf0 : s_abuf1;   // (sc+1)&1
                for (int i = tid - 64; i < SC4; i += 448) dst[i] = src[i];
            }
        } else if (tid < B) {
            // consumer: wave 0 chain over this superchunk
            const float4* sb = (sc & 1) ? s_abuf1 : s_abuf0;
            const int cbase = sc * cpsc;
            for (int cl = 0; cl < cpsc; ++cl) {
                s_ci[(cbase + cl) * B + tid] = integ;
                float4 rb[16];
#pragma unroll
                for (int j = 0; j < 16; ++j)
                    rb[j] = sb[(cl * 16 + j) * B + tid];
                __builtin_amdgcn_sched_barrier(0);   // pin reads before chain
#pragma unroll
                for (int j = 0; j < 16; ++j) {
                    integ = fract_exact(integ + rb[j].x);
                    integ = fract_exact(integ + rb[j].y);
                    integ = fract_exact(integ + rb[j].z);
                    integ = fract_exact(integ + rb[j].w);
                }
            }
        }
        __syncthreads();
    }
    if (tid < B) integ_out[tid] = integ;

    // ---- Phase C: bit-exact replay, all threads ----
    for (int w = tid; w < nchunk * B; w += 512) {
        const int c = w / B, b = w - c * B;    // b fastest -> coalesced
        float ig = s_ci[w];
        unsigned long long m = 0;
        for (int j = 0; j < 16; ++j) {
            const float4 av4 = aT4[(size_t)(c * 16 + j) * B + b];
            const float av[4] = {av4.x, av4.y, av4.z, av4.w};
            float gv[4];
#pragma unroll
            for (int k = 0; k < 4; ++k) {
                const int idx = j * 4 + k;
                const float alpha = av[k];
                const float s   = ig + alpha;      // exact ref op order
                const bool fire = (s >= THRESH);
                const float sm1 = s - 1.0f;
                ig = fire ? sm1 : s;
                gv[k] = fire ? sm1 : alpha;        // == reference rem to 1 ulp
                m |= fire ? (1ull << idx) : 0ull;
            }
#pragma unroll
            for (int k = 0; k < 4; ++k)
                gT[(size_t)(c * 64 + j * 4 + k) * B + b] = gv[k];
        }
        s_mask[w] = m;
    }
    __syncthreads();

    // ---- tlast[b] + batch-0 fire list (wave 0) ----
    if (tid < B) {
        int tl = -1;
        for (int c = nchunk - 1; c >= 0; --c) {
            const unsigned long long mc = s_mask[c * B + tid];
            if (mc) { tl = c * 64 + 63 - __clzll(mc); break; }
        }
        tlast[tid] = tl;
    }
    if (tid < 64) {
        unsigned long long m0 = (tid < nchunk) ? s_mask[tid * B] : 0ull;
        const int pc = __popcll(m0);
        int x = pc;
#pragma unroll
        for (int d = 1; d < 64; d <<= 1) {
            const int y = __shfl_up(x, d);
            if (tid >= d) x += y;
        }
        if (tid == 63) s_nf = x;
        if (tid == 0)  s_f0 = (int)(m0 & 1ull);
        int r = x - pc;
        while (m0) {
            const int p = __ffsll(m0) - 1;
            s_fire[r++] = tid * 64 + p;
            m0 &= m0 - 1;
        }
    }
    __syncthreads();

    // ---- per-output-row segment metadata ----
    const int nf = s_nf, f0 = s_f0;
    for (int r = tid; r < T; r += 512) {
        int st, en, fl;
        if (r < nf) {
            en = s_fire[r];
            st = (r == 0) ? 0 : s_fire[r - 1];
            fl = ((r == 0) ? 1 : 0) | 2;   // bit0: add frame0, bit1: end is a fire
        } else {                            // padding row -> frames[0][0]
            st = 0; en = 0; fl = 1 | (f0 ? 2 : 0);
        }
        rowStart[r] = st; rowEnd[r] = en; rowFlags[r] = fl;
    }
}

__global__ __launch_bounds__(128) void cif_out_kernel(
    const float* __restrict__ hidden,   // [B,T,H]
    const float* __restrict__ frame0,   // [B,H]
    const float* __restrict__ gT,       // [T][B]
    const float* __restrict__ alphas,   // [B,T] (batch-0 row used for wend)
    const int* __restrict__ rowStart, const int* __restrict__ rowEnd,
    const int* __restrict__ rowFlags, const int* __restrict__ tlast,
    float* __restrict__ out_sel,        // [T,H]
    float* __restrict__ frame_out,      // [B,H]
    int B, int T, int H)
{
    const int blk = blockIdx.x;

    if (blk < T) {
        const int r = blk;
        const int start = rowStart[r], end = rowEnd[r], fl = rowFlags[r];
        const float a  = alphas[end];                  // batch 0
        const float ge = gT[(size_t)end * B];
        const float wend = (fl & 2) ? (a - ge) : a;    // cur at end
        for (int h0 = threadIdx.x * 4; h0 < H; h0 += 128 * 4) {
            float4 acc = (fl & 1) ? *reinterpret_cast<const float4*>(frame0 + h0)
                                  : make_float4(0.f, 0.f, 0.f, 0.f);
            for (int s = start; s < end; ++s) {
                const float  w  = gT[(size_t)s * B];
                const float4 hv = *reinterpret_cast<const float4*>(hidden + (size_t)s * H + h0);
                acc.x += w * hv.x; acc.y += w * hv.y;
                acc.z += w * hv.z; acc.w += w * hv.w;
            }
            const float4 hv = *reinterpret_cast<const float4*>(hidden + (size_t)end * H + h0);
            acc.x += wend * hv.x; acc.y += wend * hv.y;
            acc.z += wend * hv.z; acc.w += wend * hv.w;
            *reinterpret_cast<float4*>(out_sel + (size_t)r * H + h0) = acc;
        }
    } else {
        const int b  = blk - T;
        const int tl = tlast[b];
        const int start = (tl < 0) ? 0 : tl;
        const float* hb = hidden + (size_t)b * T * H;
        for (int h0 = threadIdx.x * 4; h0 < H; h0 += 128 * 4) {
            float4 acc = (tl < 0) ? *reinterpret_cast<const float4*>(frame0 + (size_t)b * H + h0)
                                  : make_float4(0.f, 0.f, 0.f, 0.f);
            for (int s = start; s < T; ++s) {
                const float  w  = gT[(size_t)s * B + b];
                const float4 hv = *reinterpret_cast<const float4*>(hb + (size_t)s * H + h0);
                acc.x += w * hv.x; acc.y += w * hv.y;
                acc.z += w * hv.z; acc.w += w * hv.w;
            }
            *reinterpret_cast<float4*>(frame_out + (size_t)b * H + h0) = acc;
        }
    }
}

extern "C" void kernel_launch(void* const* d_in, const int* in_sizes, int n_in,
                              void* d_out, int out_size, void* d_ws, size_t ws_size,
                              hipStream_t stream) {
    const float* hidden    = (const float*)d_in[0]; // [B,T,H]
    const float* alphas    = (const float*)d_in[1]; // [B,T]
    const float* integrate = (const float*)d_in[2]; // [B]
    const float* frame     = (const float*)d_in[3]; // [B,H]

    const int B = in_sizes[2];
    const int T = in_sizes[1] / B;
    const int H = in_sizes[3] / B;

    float* out       = (float*)d_out;
    float* out_sel   = out;                     // T*H
    float* integ_out = out + (size_t)T * H;     // B
    float* frame_out = integ_out + B;           // B*H

    char* ws = (char*)d_ws;
    float4* aT4   = (float4*)ws;  ws += sizeof(float) * (size_t)B * T;
    float*  gT    = (float*)ws;   ws += sizeof(float) * (size_t)B * T;
    int* rowStart = (int*)ws;     ws += sizeof(int) * T;
    int* rowEnd   = (int*)ws;     ws += sizeof(int) * T;
    int* rowFlags = (int*)ws;     ws += sizeof(int) * T;
    int* tlast    = (int*)ws;     ws += sizeof(int) * B;

    cif_prep_kernel<<<1, 512, 0, stream>>>(
        (const float4*)alphas, integrate, aT4, gT,
        rowStart, rowEnd, rowFlags, tlast, integ_out, B, T);

    cif_out_kernel<<<T + B, 128, 0, stream>>>(
        hidden, frame, gT, alphas, rowStart, rowEnd, rowFlags, tlast,
        out_sel, frame_out, B, T, H);
}

// Round 7
// 212.892 us; speedup vs baseline: 1.1428x; 1.0696x over previous
//
#include <hip/hip_runtime.h>

// CIF (continuous integrate-and-fire) — MI355X
//
// d_out layout: [0..T*H) frame_sel ; [T*H..T*H+B) integ_new ; then [B*H) frame_new
//
// K1 prep (ONE block x 512 threads):
//   B: producer/consumer superchunk pipeline, transpose-on-the-fly (no global
//      transpose pass, no aT4 workspace). Waves 1..7 read alphas [B,T] rows
//      coalesced and write float4 granules into the idle LDS buffer in
//      transposed [t4][B] layout, while wave 0 advances the irreducible serial
//      recurrence  s = integ + alpha ; integ = fract(s)  (bit-exact vs
//      reference:  fire = s>=1 ; integ' = fire ? s-1 : s  for s in [0,2),
//      Sterbenz) out of the current buffer. One barrier per superchunk.
//      Chain loads 16 float4/chunk LDS->reg, pinned with sched_barrier(0)
//      (R4/R5 lesson: source-level global prefetch gets sunk by LLVM;
//      cross-wave LDS staging cannot be). Chunk-boundary integ -> s_ci.
//   C: replay, thread (b,c) replays chunk c of batch b bit-exactly from s_ci.
//      gT is [B][T]: both the alphas reads and gT writes are per-thread
//      contiguous float4 (coalesced across consecutive c at fixed b).
//      Then batch-0 fire list (popcount + wave prefix scan), tlast[b],
//      per-output-row segment metadata.
// K2 out: parallel segment sums (same structure since R1 — absmax 0 every
//      round); only change: gT indexed as [B][T].

#define THRESH 1.0f
#define MAXB   64
#define MAXT   2048
#define MAXCH  (MAXT / 64)
#define SC4    2048            // float4 granules per superchunk buffer (32 KB)

__device__ __forceinline__ float fract_exact(float x) {
    float r; asm("v_fract_f32 %0, %1" : "=v"(r) : "v"(x)); return r;
}

__global__ __launch_bounds__(512, 2) void cif_prep_kernel(
    const float4* __restrict__ a4g,     // alphas as float4, [B * T/4]
    const float*  __restrict__ alphas,  // alphas scalar view
    const float*  __restrict__ integ0,  // [B]
    float*  __restrict__ gT,            // ws [B][T]
    int* __restrict__ rowStart, int* __restrict__ rowEnd, int* __restrict__ rowFlags, // [T]
    int* __restrict__ tlast,            // [B]
    float* __restrict__ integ_out,      // d_out + T*H
    int B, int T)
{
    const int tid = threadIdx.x;
    const int T4 = T >> 2;
    const int nchunk = T >> 6;

    __shared__ float4             s_abuf0[SC4];        // 32 KB
    __shared__ float4             s_abuf1[SC4];        // 32 KB
    __shared__ float              s_ci[MAXCH * MAXB];  // chunk-boundary integ
    __shared__ unsigned long long s_mask[MAXCH * MAXB];// per-chunk fire masks
    __shared__ int                s_fire[MAXT];
    __shared__ int                s_nf, s_f0;

    // ---- Phase B: superchunk pipeline with on-the-fly transpose ----
    const int G  = SC4;                  // granules per superchunk (= SPS/4 * B)
    const int GP = G / B;                // granules per batch per superchunk (64)
    const int SPS = GP * 4;              // time steps per superchunk (256)
    const int NSC = T / SPS;             // superchunks (8)
    const int cpsc = SPS >> 6;           // 64-step chunks per superchunk (4)

    // preload superchunk 0 (all threads; coalesced global read per batch-row)
    for (int i = tid; i < G; i += 512) {
        const int b = i / GP, t4l = i - b * GP;
        s_abuf0[t4l * B + b] = a4g[b * T4 + t4l];
    }
    __syncthreads();

    float integ = (tid < B) ? integ0[tid] : 0.0f;

    for (int sc = 0; sc < NSC; ++sc) {
        if (tid >= 64) {
            if (sc + 1 < NSC) {
                float4* dst = (sc & 1) ? s_abuf0 : s_abuf1;   // (sc+1)&1
                const int t4base = (sc + 1) * GP;
                for (int i = tid - 64; i < G; i += 448) {
                    const int b = i / GP, t4l = i - b * GP;
                    dst[t4l * B + b] = a4g[b * T4 + t4base + t4l];
                }
            }
        } else if (tid < B) {
            const float4* sb = (sc & 1) ? s_abuf1 : s_abuf0;
            const int cbase = sc * cpsc;
            for (int cl = 0; cl < cpsc; ++cl) {
                s_ci[(cbase + cl) * B + tid] = integ;
                float4 rb[16];
#pragma unroll
                for (int j = 0; j < 16; ++j)
                    rb[j] = sb[(cl * 16 + j) * B + tid];
                __builtin_amdgcn_sched_barrier(0);   // pin reads before chain
#pragma unroll
                for (int j = 0; j < 16; ++j) {
                    integ = fract_exact(integ + rb[j].x);
                    integ = fract_exact(integ + rb[j].y);
                    integ = fract_exact(integ + rb[j].z);
                    integ = fract_exact(integ + rb[j].w);
                }
            }
        }
        __syncthreads();
    }
    if (tid < B) integ_out[tid] = integ;

    // ---- Phase C: bit-exact replay; thread (b,c), contiguous reads/writes ----
    float4* gT4 = (float4*)gT;
    for (int w = tid; w < nchunk * B; w += 512) {
        const int b = w / nchunk, c = w - b * nchunk;
        float ig = s_ci[c * B + b];
        unsigned long long m = 0;
        for (int j = 0; j < 16; ++j) {
            const float4 av4 = a4g[b * T4 + c * 16 + j];
            const float av[4] = {av4.x, av4.y, av4.z, av4.w};
            float gv[4];
#pragma unroll
            for (int k = 0; k < 4; ++k) {
                const int idx = j * 4 + k;
                const float alpha = av[k];
                const float s   = ig + alpha;      // exact ref op order
                const bool fire = (s >= THRESH);
                const float sm1 = s - 1.0f;
                ig = fire ? sm1 : s;
                gv[k] = fire ? sm1 : alpha;        // == reference rem to 1 ulp
                m |= fire ? (1ull << idx) : 0ull;
            }
            gT4[b * T4 + c * 16 + j] = make_float4(gv[0], gv[1], gv[2], gv[3]);
        }
        s_mask[c * B + b] = m;
    }
    __syncthreads();

    // ---- tlast[b] + batch-0 fire list (wave 0) ----
    if (tid < B) {
        int tl = -1;
        for (int c = nchunk - 1; c >= 0; --c) {
            const unsigned long long mc = s_mask[c * B + tid];
            if (mc) { tl = c * 64 + 63 - __clzll(mc); break; }
        }
        tlast[tid] = tl;
    }
    if (tid < 64) {
        unsigned long long m0 = (tid < nchunk) ? s_mask[tid * B] : 0ull;
        const int pc = __popcll(m0);
        int x = pc;
#pragma unroll
        for (int d = 1; d < 64; d <<= 1) {
            const int y = __shfl_up(x, d);
            if (tid >= d) x += y;
        }
        if (tid == 63) s_nf = x;
        if (tid == 0)  s_f0 = (int)(m0 & 1ull);
        int r = x - pc;
        while (m0) {
            const int p = __ffsll(m0) - 1;
            s_fire[r++] = tid * 64 + p;
            m0 &= m0 - 1;
        }
    }
    __syncthreads();

    // ---- per-output-row segment metadata ----
    const int nf = s_nf, f0 = s_f0;
    for (int r = tid; r < T; r += 512) {
        int st, en, fl;
        if (r < nf) {
            en = s_fire[r];
            st = (r == 0) ? 0 : s_fire[r - 1];
            fl = ((r == 0) ? 1 : 0) | 2;   // bit0: add frame0, bit1: end is a fire
        } else {                            // padding row -> frames[0][0]
            st = 0; en = 0; fl = 1 | (f0 ? 2 : 0);
        }
        rowStart[r] = st; rowEnd[r] = en; rowFlags[r] = fl;
    }
}

__global__ __launch_bounds__(128) void cif_out_kernel(
    const float* __restrict__ hidden,   // [B,T,H]
    const float* __restrict__ frame0,   // [B,H]
    const float* __restrict__ gT,       // [B][T]
    const float* __restrict__ alphas,   // [B,T] (batch-0 row used for wend)
    const int* __restrict__ rowStart, const int* __restrict__ rowEnd,
    const int* __restrict__ rowFlags, const int* __restrict__ tlast,
    float* __restrict__ out_sel,        // [T,H]
    float* __restrict__ frame_out,      // [B,H]
    int B, int T, int H)
{
    const int blk = blockIdx.x;

    if (blk < T) {
        const int r = blk;
        const int start = rowStart[r], end = rowEnd[r], fl = rowFlags[r];
        const float a  = alphas[end];                  // batch 0
        const float ge = gT[end];                      // batch 0 row of gT
        const float wend = (fl & 2) ? (a - ge) : a;    // cur at end
        for (int h0 = threadIdx.x * 4; h0 < H; h0 += 128 * 4) {
            float4 acc = (fl & 1) ? *reinterpret_cast<const float4*>(frame0 + h0)
                                  : make_float4(0.f, 0.f, 0.f, 0.f);
            for (int s = start; s < end; ++s) {
                const float  w  = gT[s];
                const float4 hv = *reinterpret_cast<const float4*>(hidden + (size_t)s * H + h0);
                acc.x += w * hv.x; acc.y += w * hv.y;
                acc.z += w * hv.z; acc.w += w * hv.w;
            }
            const float4 hv = *reinterpret_cast<const float4*>(hidden + (size_t)end * H + h0);
            acc.x += wend * hv.x; acc.y += wend * hv.y;
            acc.z += wend * hv.z; acc.w += wend * hv.w;
            *reinterpret_cast<float4*>(out_sel + (size_t)r * H + h0) = acc;
        }
    } else {
        const int b  = blk - T;
        const int tl = tlast[b];
        const int start = (tl < 0) ? 0 : tl;
        const float* hb = hidden + (size_t)b * T * H;
        const float* gb = gT + (size_t)b * T;
        for (int h0 = threadIdx.x * 4; h0 < H; h0 += 128 * 4) {
            float4 acc = (tl < 0) ? *reinterpret_cast<const float4*>(frame0 + (size_t)b * H + h0)
                                  : make_float4(0.f, 0.f, 0.f, 0.f);
            for (int s = start; s < T; ++s) {
                const float  w  = gb[s];
                const float4 hv = *reinterpret_cast<const float4*>(hb + (size_t)s * H + h0);
                acc.x += w * hv.x; acc.y += w * hv.y;
                acc.z += w * hv.z; acc.w += w * hv.w;
            }
            *reinterpret_cast<float4*>(frame_out + (size_t)b * H + h0) = acc;
        }
    }
}

extern "C" void kernel_launch(void* const* d_in, const int* in_sizes, int n_in,
                              void* d_out, int out_size, void* d_ws, size_t ws_size,
                              hipStream_t stream) {
    const float* hidden    = (const float*)d_in[0]; // [B,T,H]
    const float* alphas    = (const float*)d_in[1]; // [B,T]
    const float* integrate = (const float*)d_in[2]; // [B]
    const float* frame     = (const float*)d_in[3]; // [B,H]

    const int B = in_sizes[2];
    const int T = in_sizes[1] / B;
    const int H = in_sizes[3] / B;

    float* out       = (float*)d_out;
    float* out_sel   = out;                     // T*H
    float* integ_out = out + (size_t)T * H;     // B
    float* frame_out = integ_out + B;           // B*H

    char* ws = (char*)d_ws;
    float*  gT    = (float*)ws;   ws += sizeof(float) * (size_t)B * T;
    int* rowStart = (int*)ws;     ws += sizeof(int) * T;
    int* rowEnd   = (int*)ws;     ws += sizeof(int) * T;
    int* rowFlags = (int*)ws;     ws += sizeof(int) * T;
    int* tlast    = (int*)ws;     ws += sizeof(int) * B;

    cif_prep_kernel<<<1, 512, 0, stream>>>(
        (const float4*)alphas, alphas, integrate, gT,
        rowStart, rowEnd, rowFlags, tlast, integ_out, B, T);

    cif_out_kernel<<<T + B, 128, 0, stream>>>(
        hidden, frame, gT, alphas, rowStart, rowEnd, rowFlags, tlast,
        out_sel, frame_out, B, T, H);
}